// Round 1
// baseline (129.923 us; speedup 1.0000x reference)
//
#include <hip/hip_runtime.h>
#include <math.h>

// Problem constants (N=M=8192, d=64, P=64, N_FT=1024 -> folded K=512)
#define N_SRC 8192
#define D_DIM 64
#define P_SL  64
#define KH    512

// ws layout (float offsets)
#define WS_NM  0                         // norm_max as float bits (atomicMax on uint)
#define WS_CNT 1                         // active frequency count (uint)
#define WS_HL  16                        // h values of active freqs [512]
#define WS_WL  (16 + KH)                 // folded weights (incl. 1/P) [512]
#define WS_CS  (16 + 2*KH)               // C,S per (p, kidx): P*KH*2
#define WS_A   (WS_CS + P_SL*KH*2)       // projections of x: P*N
#define WS_B   (WS_A + P_SL*N_SRC)       // projections of y: P*N

__device__ __forceinline__ void sincos2pi(float t, float& s, float& c) {
    // v_sin_f32 / v_cos_f32 take input in REVOLUTIONS; fract for valid range.
    float f = __builtin_amdgcn_fractf(t);
    s = __builtin_amdgcn_sinf(f);
    c = __builtin_amdgcn_cosf(f);
}

// K1: norm_max over all rows of x and y (16384 rows of 64 floats)
__global__ __launch_bounds__(256) void k_normmax(const float* __restrict__ x,
                                                 const float* __restrict__ y,
                                                 float* __restrict__ ws) {
    int r = blockIdx.x * 256 + threadIdx.x;  // exactly 0..16383
    const float* row = (r < N_SRC) ? (x + (size_t)r * D_DIM)
                                   : (y + (size_t)(r - N_SRC) * D_DIM);
    const float4* r4 = (const float4*)row;
    float ss = 0.f;
#pragma unroll
    for (int j = 0; j < D_DIM / 4; ++j) {
        float4 v = r4[j];
        ss = fmaf(v.x, v.x, ss); ss = fmaf(v.y, v.y, ss);
        ss = fmaf(v.z, v.z, ss); ss = fmaf(v.w, v.w, ss);
    }
    float nm = sqrtf(ss);
    for (int o = 32; o; o >>= 1) nm = fmaxf(nm, __shfl_xor(nm, o, 64));
    if ((threadIdx.x & 63) == 0)
        atomicMax((unsigned int*)(ws + WS_NM), __float_as_uint(nm));  // all positive
}

// K2: kft table in f32 (matches reference log-space formula), fold +-k symmetry,
// compact the non-negligible band into (h, w) list. Order is irrelevant (summation).
__global__ void k_kft(const float* __restrict__ scale, float* __restrict__ ws) {
    int k = threadIdx.x + 1;  // 1..512
    float nm = ws[WS_NM];
    float sf = 0.3f / nm;
    float sr = scale[0] * sf;
    float s2 = sr * sr;
    float a = 19.7392088f * s2;  // 2*pi^2*sigma^2
    float logv = 32.0f * logf(a) + 63.0f * logf((float)k)
               - a * (float)(k * k) - 78.0922235f;  // lgamma(32)
    float v = expf(logv);
    float wk = ((k == KH) ? 1.0f : 2.0f) * v * (1.0f / (float)P_SL);
    if (v > 1e-18f) {
        unsigned idx = atomicAdd((unsigned int*)(ws + WS_CNT), 1u);
        ws[WS_HL + idx] = (float)k;
        ws[WS_WL + idx] = wk;
    }
}

// K3: projections A[p][n] = sf * (x_n . xi_p), B likewise for y.
__global__ __launch_bounds__(256) void k_proj(const float* __restrict__ x,
                                              const float* __restrict__ y,
                                              const float* __restrict__ xis,
                                              float* __restrict__ ws) {
    __shared__ float xi[D_DIM];
    int p = blockIdx.y;
    int which = blockIdx.z;
    const float* src = which ? y : x;
    float* dst = ws + (which ? WS_B : WS_A);
    if (threadIdx.x < D_DIM) xi[threadIdx.x] = xis[p * D_DIM + threadIdx.x];
    __syncthreads();
    float sf = 0.3f / ws[WS_NM];
    int n = blockIdx.x * 256 + threadIdx.x;
    const float4* r4 = (const float4*)(src + (size_t)n * D_DIM);
    const float4* xi4 = (const float4*)xi;
    float acc = 0.f;
#pragma unroll
    for (int j = 0; j < D_DIM / 4; ++j) {
        float4 v = r4[j]; float4 u = xi4[j];
        acc = fmaf(v.x, u.x, acc); acc = fmaf(v.y, u.y, acc);
        acc = fmaf(v.z, u.z, acc); acc = fmaf(v.w, u.w, acc);
    }
    dst[p * N_SRC + n] = sf * acc;
}

// K4: adjoint NDFT. C_pk = sum_n w_n cos(2 pi k a_pn), S_pk = sum sin.
// Block = (slice p, chunk of 512 source points). Thread = (kslot 0..63, stripe 0..3).
__global__ __launch_bounds__(256) void k_adjoint(const float* __restrict__ xw,
                                                 float* __restrict__ ws) {
    __shared__ float a_l[512], w_l[512];
    int p = blockIdx.y, c = blockIdx.x;
    for (int i = threadIdx.x; i < 512; i += 256) {
        a_l[i] = ws[WS_A + p * N_SRC + c * 512 + i];
        w_l[i] = xw[c * 512 + i];
    }
    __syncthreads();
    int kact = (int)((unsigned int*)ws)[WS_CNT];
    int kslot = threadIdx.x >> 2, stripe = threadIdx.x & 3;
    for (int kidx = kslot; kidx < kact; kidx += 64) {
        float h = ws[WS_HL + kidx];
        float ca = 0.f, sa = 0.f;
#pragma unroll 4
        for (int j = stripe; j < 512; j += 4) {  // LDS broadcast reads, no conflicts
            float t = h * a_l[j];
            float s, cc; sincos2pi(t, s, cc);
            float wv = w_l[j];
            ca = fmaf(wv, cc, ca);
            sa = fmaf(wv, s, sa);
        }
        // reduce the 4 stripes (same-kidx lanes are contiguous in the wave)
        ca += __shfl_xor(ca, 1, 64); ca += __shfl_xor(ca, 2, 64);
        sa += __shfl_xor(sa, 1, 64); sa += __shfl_xor(sa, 2, 64);
        if (stripe == 0) {
            atomicAdd(ws + WS_CS + (p * KH + kidx) * 2 + 0, ca);
            atomicAdd(ws + WS_CS + (p * KH + kidx) * 2 + 1, sa);
        }
    }
}

// K5: forward NDFT. out_m += sum_k w_k (C cos(2 pi k b) + S sin(2 pi k b)).
__global__ __launch_bounds__(256) void k_forward(float* __restrict__ out,
                                                 float* __restrict__ ws) {
    __shared__ float h_l[KH], wc_l[KH], wsn_l[KH];
    int p = blockIdx.y;
    int kact = (int)((unsigned int*)ws)[WS_CNT];
    for (int i = threadIdx.x; i < kact; i += 256) {
        h_l[i] = ws[WS_HL + i];
        float wk = ws[WS_WL + i];
        wc_l[i]  = wk * ws[WS_CS + (p * KH + i) * 2 + 0];
        wsn_l[i] = wk * ws[WS_CS + (p * KH + i) * 2 + 1];
    }
    __syncthreads();
    int m = blockIdx.x * 256 + threadIdx.x;
    float b = ws[WS_B + p * N_SRC + m];
    float sum = 0.f;
    for (int i = 0; i < kact; ++i) {  // LDS same-address broadcast
        float t = b * h_l[i];
        float s, cc; sincos2pi(t, s, cc);
        sum = fmaf(wc_l[i], cc, sum);
        sum = fmaf(wsn_l[i], s, sum);
    }
    atomicAdd(out + m, sum);
}

extern "C" void kernel_launch(void* const* d_in, const int* in_sizes, int n_in,
                              void* d_out, int out_size, void* d_ws, size_t ws_size,
                              hipStream_t stream) {
    const float* x     = (const float*)d_in[0];
    const float* y     = (const float*)d_in[1];
    const float* xw    = (const float*)d_in[2];
    const float* scale = (const float*)d_in[3];
    const float* xis   = (const float*)d_in[4];
    float* ws  = (float*)d_ws;
    float* out = (float*)d_out;

    // zero: norm_max + count, C/S accumulators, output
    hipMemsetAsync(ws, 0, 8, stream);
    hipMemsetAsync(ws + WS_CS, 0, (size_t)P_SL * KH * 2 * sizeof(float), stream);
    hipMemsetAsync(out, 0, (size_t)N_SRC * sizeof(float), stream);

    k_normmax<<<dim3(64),          dim3(256), 0, stream>>>(x, y, ws);
    k_kft    <<<dim3(1),           dim3(512), 0, stream>>>(scale, ws);
    k_proj   <<<dim3(32, 64, 2),   dim3(256), 0, stream>>>(x, y, xis, ws);
    k_adjoint<<<dim3(16, 64),      dim3(256), 0, stream>>>(xw, ws);
    k_forward<<<dim3(32, 64),      dim3(256), 0, stream>>>(out, ws);
}